// Round 7
// baseline (416.421 us; speedup 1.0000x reference)
//
#include <hip/hip_runtime.h>
#include <hip/hip_bf16.h>

// DoReFa conv2d, MI355X.
// xq = round(min(1,|x|)*7)/7  -> integer k in 0..7, exact in bf16
// wq = sign(W)*E, E = mean|W| -> sign in {-1,0,+1}, exact in bf16
// y[p,c] = (E/7) * sum_k( sign * k ) + b[c]   (integer sum exact in fp32 acc)
// Implicit GEMM via mfma_f32_16x16x32_bf16, weights as A operand, pixels as B.
// Persistent blocks: 8 y-consecutive tiles each, double-buffered LDS,
// reg-staged async loads (T14): load(t+1) issues before compute(t).
// Weight matrix rows channel-permuted so each lane stores 32 contiguous bytes.

typedef __bf16 bf16x8 __attribute__((ext_vector_type(8)));
typedef float f32x4 __attribute__((ext_vector_type(4)));

#define TW 32   // output tile width  (x)
#define TH 16   // output tile height (y)
#define LW 34   // input tile width with halo
#define LH 18   // input tile height with halo
#define PST 48  // bytes per pixel in LDS (32B data + 16B pad)
#define NPIX (LH * LW)   // 612 pixels per tile
#define NLD  (NPIX * 4)  // 2448 float4 stage-loads per tile
#define NIT  10          // ceil(NLD / 256)
#define NT   8           // y-tiles per block

__device__ __forceinline__ unsigned short quant3(float v) {
  // k = rint(min(1,|v|)*7) in {0..7}; bf16 bits = fp32 bits >> 16 (exact small ints)
  float t = rintf(fminf(fabsf(v), 1.0f) * 7.0f);
  union { float f; unsigned int u; } cv; cv.f = t;
  return (unsigned short)(cv.u >> 16);
}

// scale = mean|W|/7 -> ws[0]; weight sign table (bf16) at ws+16B,
// layout [pair 5][nf 2][lane 64][j 8]. Matrix row r = lane&15 maps to output
// channel c = 8*(r>>2) + (r&3) + 4*nf  (perm so D rows 4g..4g+3 of the two
// nf-MFMAs give lane channels 8g..8g+3 / 8g+4..8g+7 -> contiguous stores).
// k-group g=lane>>4: pair p<4 -> pos=2p+(g>>1), ci=(g&1)*8+j; pair 4 -> pos 8
// for g<2, zeros for g>=2 (K padding 144->160).
__global__ void prep_kernel(const float* __restrict__ W, float* __restrict__ ws) {
  __shared__ float red[256];
  int tid = threadIdx.x;
  float s = 0.f;
  for (int i = tid; i < 4608; i += 256) s += fabsf(W[i]);
  red[tid] = s;
  __syncthreads();
  for (int off = 128; off > 0; off >>= 1) {
    if (tid < off) red[tid] += red[tid + off];
    __syncthreads();
  }
  float E = red[0] * (1.0f / 4608.0f);
  if (tid == 0) ws[0] = E * (1.0f / 7.0f);
  unsigned short* bf = (unsigned short*)(ws + 4);
  for (int i = tid; i < 5 * 2 * 64 * 8; i += 256) {
    int j  = i & 7;
    int l  = (i >> 3) & 63;
    int nf = (i >> 9) & 1;
    int p  = i >> 10;
    int g  = l >> 4;
    int r  = l & 15;
    float v = 0.f;
    if (p < 4 || g < 2) {
      int pos = (p < 4) ? (2 * p + (g >> 1)) : 8;       // kh*3+kw
      int ci  = (g & 1) * 8 + j;
      int c   = ((r >> 2) << 3) + (r & 3) + nf * 4;     // channel perm
      float w = W[(pos * 16 + ci) * 32 + c];            // W[kh][kw][ci][c]
      v = (w > 0.f) ? 1.f : ((w < 0.f) ? -1.f : 0.f);
    }
    union { float f; unsigned int u; } cv; cv.f = v;
    bf[i] = (unsigned short)(cv.u >> 16);
  }
}

__global__ __launch_bounds__(256) void conv_kernel(
    const float* __restrict__ x, const float* __restrict__ bias,
    const float* __restrict__ ws, float* __restrict__ out) {
  __shared__ __align__(16) char lds[2][NPIX * PST];  // 2 x 29376 B
  const unsigned short* bfr = (const unsigned short*)(ws + 4);

  int bid = blockIdx.x;          // 512 blocks: 4 y-groups x 16 x-tiles x 8 images
  int tyg = bid & 3;             // y-group: tiles tyg*8 .. tyg*8+7
  int txt = (bid >> 2) & 15;
  int n   = bid >> 6;
  int gx0 = txt * TW;
  int tid  = threadIdx.x;
  int lane = tid & 63;
  int wv   = tid >> 6;           // wave 0..3 owns tile rows wv*4..wv*4+3
  int g    = lane >> 4;
  int m    = lane & 15;

  // Weight fragments (uniform across blocks, L2-served).
  bf16x8 bfrag[5][2];
#pragma unroll
  for (int p = 0; p < 5; ++p)
#pragma unroll
    for (int nf = 0; nf < 2; ++nf)
      bfrag[p][nf] = *(const bf16x8*)(bfr + ((p * 2 + nf) * 64 + lane) * 8);
  float scale = ws[0];
  float4 bias0 = ((const float4*)bias)[2 * g];      // channels 8g..8g+3
  float4 bias1 = ((const float4*)bias)[2 * g + 1];  // channels 8g+4..8g+7

  const float* xn = x + (size_t)n * (512 * 512 * 16);

  // Per-lane LDS offsets for the 5 K-pairs of the pixel (B) operand.
  int laneoff[5];
#pragma unroll
  for (int p = 0; p < 5; ++p) {
    int pos = (p < 4) ? (2 * p + (g >> 1)) : 8;
    int kh = pos / 3, kw = pos - kh * 3;
    laneoff[p] = (kh * LW + kw) * PST + (g & 1) * 16 + m * PST;
  }

  float4 sreg[NIT];  // staged raw input for the next tile (statically indexed)

  auto issue_loads = [&](int t) {
    int gy0 = (tyg * NT + t) * TH;
#pragma unroll
    for (int it = 0; it < NIT; ++it) {
      int i = tid + it * 256;
      float4 v = make_float4(0.f, 0.f, 0.f, 0.f);
      if (i < NLD) {
        int cig = i & 3;
        int pix = i >> 2;
        int py = pix / LW;
        int px = pix - py * LW;
        int gy = gy0 - 1 + py, gx = gx0 - 1 + px;
        if (gy >= 0 && gy < 512 && gx >= 0 && gx < 512)
          v = *(const float4*)(xn + ((gy << 9) + gx) * 16 + cig * 4);
      }
      sreg[it] = v;
    }
  };

  auto write_tile = [&](int buf) {
#pragma unroll
    for (int it = 0; it < NIT; ++it) {
      int i = tid + it * 256;
      if (i < NLD) {
        int cig = i & 3;
        int pix = i >> 2;
        ushort4 q;
        q.x = quant3(sreg[it].x); q.y = quant3(sreg[it].y);
        q.z = quant3(sreg[it].z); q.w = quant3(sreg[it].w);
        *(ushort4*)(&lds[buf][pix * PST + cig * 8]) = q;
      }
    }
  };

  issue_loads(0);
  write_tile(0);

  for (int t = 0; t < NT; ++t) {
    __syncthreads();                       // lds[t&1] ready for all waves
    if (t + 1 < NT) issue_loads(t + 1);    // async: latency hides under MFMA
    int gy0 = (tyg * NT + t) * TH;
    const char* buf = lds[t & 1];
#pragma unroll
    for (int r = 0; r < 4; ++r) {
      int ty = wv * 4 + r;
#pragma unroll
      for (int xt = 0; xt < 2; ++xt) {
        int tx = xt * 16;
        int base = (ty * LW + tx) * PST;
        f32x4 acc0 = {0.f, 0.f, 0.f, 0.f};
        f32x4 acc1 = {0.f, 0.f, 0.f, 0.f};
#pragma unroll
        for (int p = 0; p < 5; ++p) {
          bf16x8 b = *(const bf16x8*)(&buf[base + laneoff[p]]);
          acc0 = __builtin_amdgcn_mfma_f32_16x16x32_bf16(bfrag[p][0], b, acc0, 0, 0, 0);
          acc1 = __builtin_amdgcn_mfma_f32_16x16x32_bf16(bfrag[p][1], b, acc1, 0, 0, 0);
        }
        // D: col = lane&15 = pixel (x=tx+m); rows 4g+j -> channels 8g+j (nf=0),
        // 8g+4+j (nf=1) via the prep channel perm -> 32B contiguous per lane.
        float4 o0, o1;
        o0.x = acc0[0] * scale + bias0.x;  o0.y = acc0[1] * scale + bias0.y;
        o0.z = acc0[2] * scale + bias0.z;  o0.w = acc0[3] * scale + bias0.w;
        o1.x = acc1[0] * scale + bias1.x;  o1.y = acc1[1] * scale + bias1.y;
        o1.z = acc1[2] * scale + bias1.z;  o1.w = acc1[3] * scale + bias1.w;
        float* op = out + (((size_t)((n << 9) + (gy0 + ty)) << 9) + (gx0 + tx + m)) * 32 + (g << 3);
        *(float4*)op = o0;
        *(float4*)(op + 4) = o1;
      }
    }
    if (t + 1 < NT) write_tile((t + 1) & 1);  // other buffer; sync'd next iter
  }
}

extern "C" void kernel_launch(void* const* d_in, const int* in_sizes, int n_in,
                              void* d_out, int out_size, void* d_ws, size_t ws_size,
                              hipStream_t stream) {
  const float* x = (const float*)d_in[0];
  const float* W = (const float*)d_in[1];
  const float* b = (const float*)d_in[2];
  float* out = (float*)d_out;
  float* ws  = (float*)d_ws;

  prep_kernel<<<1, 256, 0, stream>>>(W, ws);
  conv_kernel<<<512, 256, 0, stream>>>(x, b, ws, out);
}